// Round 1
// baseline (12627.415 us; speedup 1.0000x reference)
//
#include <hip/hip_runtime.h>
#include <hip/hip_bf16.h>

// ---------------------------------------------------------------------------
// Decoder_20435454395154
//   cond = z + theta@W_theta^T + b_theta                    (32x256)
//   x    = cond @ W_dec^T + b_dec                           (32x65536)
//   GroupNorm(8,64) -> inp[b,t,64] = xs + shifted emb       (bf16)
//   weight-normed LSTM, 3072 steps, D_H=256                 (the hot loop)
//   out  = hs @ W_ro^T + b_ro, permuted to [b,v,3,32,32]    (f32, 100MB)
//
// LSTM layout: 8 blocks x 4 waves = 32 waves. Wave (s,m,q):
//   batches m*16..m*16+15, h-dims s*32+q*16..+16, all 4 gates (i,f,g,o),
//   W_hh slice (4 gate-tiles x 16n x 256k bf16) resident in 128 VGPRs/lane,
//   W_ih slice in 32 VGPRs/lane. Gate cols lane-aligned -> c,h update is
//   lane-local fp32 (4 batches x 1 dim per lane).
// Cross-CU h exchange: hs[t] slab written with global_store_short sc0 sc1
// (write-through to MALL), per-wave flags (agent-scope atomics) in ws.
// Flag value 0x5E000000|t is never equal to the 0xAA poison pattern and each
// flag word is written exactly once per launch -> graph-replay safe.
// ---------------------------------------------------------------------------

typedef float  f32x4 __attribute__((ext_vector_type(4)));
typedef short  s16x8 __attribute__((ext_vector_type(8)));

__device__ __forceinline__ unsigned short f2bf(float f) {
  union { float f; unsigned u; } v; v.f = f;
  unsigned r = v.u + 0x7FFFu + ((v.u >> 16) & 1u);   // RNE
  return (unsigned short)(r >> 16);
}

#define B_     32
#define SEQ_   3072
#define DH_    256
#define NG_    1024     // 4*DH
#define NV_    256
#define NPIX_  1024

// ------------------------------- prologue ----------------------------------

// weight-norm row scales: rsih[r] = g_ih[r]/||v_ih[r]||, rshh likewise
__global__ void p0_norms(const float* __restrict__ v_ih, const float* __restrict__ g_ih,
                         const float* __restrict__ v_hh, const float* __restrict__ g_hh,
                         float* __restrict__ rsih, float* __restrict__ rshh) {
  const int w = (blockIdx.x * 256 + threadIdx.x) >> 6;
  const int lane = threadIdx.x & 63;
  if (w < 1024) {
    float v = v_ih[w * 64 + lane];
    float s = v * v;
    #pragma unroll
    for (int o = 32; o > 0; o >>= 1) s += __shfl_xor(s, o);
    if (lane == 0) rsih[w] = g_ih[w] * rsqrtf(s);
  } else {
    const int r = w - 1024;
    f32x4 v = *(const f32x4*)(v_hh + (size_t)r * 256 + lane * 4);
    float s = v[0]*v[0] + v[1]*v[1] + v[2]*v[2] + v[3]*v[3];
    #pragma unroll
    for (int o = 32; o > 0; o >>= 1) s += __shfl_xor(s, o);
    if (lane == 0) rshh[r] = g_hh[r] * rsqrtf(s);
  }
}

// pack W_hh into B-fragment order: [sq(16)][g(4)][ks(8)][lane(64)][8]
__global__ void p2_packWB(const float* __restrict__ v_hh, const float* __restrict__ rshh,
                          unsigned short* __restrict__ WBp) {
  const int o = blockIdx.x * 256 + threadIdx.x;
  const int j = o & 7, l = (o >> 3) & 63, ks = (o >> 9) & 7, g = (o >> 12) & 3, sq = o >> 14;
  const int r = g * 256 + (sq >> 1) * 32 + (sq & 1) * 16 + (l & 15);
  const int k = ks * 32 + (l >> 4) * 8 + j;
  WBp[o] = f2bf(v_hh[(size_t)r * 256 + k] * rshh[r]);
}

// pack W_ih: [sq(16)][g(4)][ks(2)][lane(64)][8]
__global__ void p3_packWI(const float* __restrict__ v_ih, const float* __restrict__ rsih,
                          unsigned short* __restrict__ WIp) {
  const int o = blockIdx.x * 256 + threadIdx.x;
  const int j = o & 7, l = (o >> 3) & 63, ks = (o >> 9) & 1, g = (o >> 10) & 3, sq = o >> 12;
  const int r = g * 256 + (sq >> 1) * 32 + (sq & 1) * 16 + (l & 15);
  const int k = ks * 32 + (l >> 4) * 8 + j;
  WIp[o] = f2bf(v_ih[(size_t)r * 64 + k] * rsih[r]);
}

__global__ void k1a_cond(const float* __restrict__ z, const float* __restrict__ theta,
                         const float* __restrict__ W_theta, const float* __restrict__ b_theta,
                         float* __restrict__ cond) {
  const int i = blockIdx.x * 256 + threadIdx.x;
  const int b = i >> 8, n = i & 255;
  cond[i] = z[i] + theta[b*2+0] * W_theta[n*2+0] + theta[b*2+1] * W_theta[n*2+1] + b_theta[n];
}

// x[b, r] = cond[b,:] . W_dec[r,:] + b_dec[r]; thread = row, 32 batch accs
__global__ __launch_bounds__(256) void k1b_dec(const float* __restrict__ cond,
                                               const float* __restrict__ W_dec,
                                               const float* __restrict__ b_dec,
                                               float* __restrict__ x) {
  const int r = blockIdx.x * 256 + threadIdx.x;
  float acc[32];
  const float bd = b_dec[r];
  #pragma unroll
  for (int b = 0; b < 32; ++b) acc[b] = bd;
  const f32x4* wp = (const f32x4*)(W_dec + (size_t)r * 256);
  for (int k4 = 0; k4 < 64; ++k4) {
    const f32x4 w = wp[k4];
    #pragma unroll
    for (int b = 0; b < 32; ++b) {
      const float* cp = cond + b * 256 + k4 * 4;   // wave-uniform -> s_loads
      acc[b] += w[0]*cp[0] + w[1]*cp[1] + w[2]*cp[2] + w[3]*cp[3];
    }
  }
  #pragma unroll
  for (int b = 0; b < 32; ++b) x[(size_t)b * 65536 + r] = acc[b];
}

// GroupNorm stats -> per-(b,c) affine gnA,gnB
__global__ void k1c_gnstats(const float* __restrict__ x, const float* __restrict__ gn_w,
                            const float* __restrict__ gn_b,
                            float* __restrict__ gnA, float* __restrict__ gnB) {
  __shared__ float sS[256], sQ[256];
  const int b = blockIdx.x >> 3, g = blockIdx.x & 7;
  const float* xp = x + (size_t)b * 65536 + g * 8192;
  float s = 0.f, qq = 0.f;
  for (int i = threadIdx.x; i < 8192; i += 256) { float v = xp[i]; s += v; qq += v * v; }
  sS[threadIdx.x] = s; sQ[threadIdx.x] = qq; __syncthreads();
  for (int o = 128; o > 0; o >>= 1) {
    if (threadIdx.x < o) { sS[threadIdx.x] += sS[threadIdx.x+o]; sQ[threadIdx.x] += sQ[threadIdx.x+o]; }
    __syncthreads();
  }
  if (threadIdx.x < 8) {
    const float mu  = sS[0] * (1.f / 8192.f);
    const float var = sQ[0] * (1.f / 8192.f) - mu * mu;
    const float rstd = rsqrtf(var + 1e-5f);
    const int c = g * 8 + threadIdx.x;
    const float a = gn_w[c] * rstd;
    gnA[b*64+c] = a; gnB[b*64+c] = gn_b[c] - mu * a;
  }
}

// inp[b,t,ch] = gn(x)[b,ch,p] + (t>0 ? emb[tok[t-1],ch] : 0), bf16
__global__ void k1d_inp(const float* __restrict__ x, const float* __restrict__ gnA,
                        const float* __restrict__ gnB, const float* __restrict__ emb,
                        const int* __restrict__ xt, unsigned short* __restrict__ inp) {
  __shared__ float xT[128 * 65];
  const int b = blockIdx.x >> 3, pt = blockIdx.x & 7, p0 = pt * 128;
  const int tid = threadIdx.x;
  for (int i = tid; i < 8192; i += 256) {
    const int p = i & 127, ch = i >> 7;
    float v = x[(size_t)b * 65536 + ch * 1024 + p0 + p];
    xT[p * 65 + ch] = v * gnA[b*64+ch] + gnB[b*64+ch];
  }
  __syncthreads();
  const int wave = tid >> 6, lane = tid & 63;
  for (int row = wave; row < 384; row += 4) {
    const int c3 = row / 128, p = row % 128;
    const int t = c3 * 1024 + p0 + p;
    float v = xT[p * 65 + lane];
    if (t > 0) {
      const int tok = xt[b * SEQ_ + t - 1];
      v += emb[tok * 64 + lane];
    }
    inp[((size_t)b * SEQ_ + t) * 64 + lane] = f2bf(v);
  }
}

// ------------------------------- recurrence --------------------------------

__global__ __launch_bounds__(256, 1) void k3_lstm(
    const unsigned short* __restrict__ WBp, const unsigned short* __restrict__ WIp,
    const unsigned short* __restrict__ inp, const float* __restrict__ b_ih,
    const float* __restrict__ b_hh, unsigned short* __restrict__ hs,
    unsigned int* __restrict__ flags) {
  const int s = blockIdx.x;                 // 0..7  h-dim slice
  const int tid = threadIdx.x;
  const int wave = tid >> 6, lane = tid & 63;
  const int m = wave >> 1, q = wave & 1;    // batch half, dim sub-slice
  const int col = lane & 15, quad = lane >> 4;
  const int sq = s * 2 + q;

  // resident weight fragments
  s16x8 Bf[4][8];
  #pragma unroll
  for (int g = 0; g < 4; ++g)
    #pragma unroll
    for (int ks = 0; ks < 8; ++ks)
      Bf[g][ks] = ((const s16x8*)WBp)[((sq * 4 + g) * 8 + ks) * 64 + lane];
  s16x8 WIf[4][2];
  #pragma unroll
  for (int g = 0; g < 4; ++g)
    #pragma unroll
    for (int ks = 0; ks < 2; ++ks)
      WIf[g][ks] = ((const s16x8*)WIp)[((sq * 4 + g) * 2 + ks) * 64 + lane];
  float bias[4];
  #pragma unroll
  for (int g = 0; g < 4; ++g) {
    const int n = g * 256 + s * 32 + q * 16 + col;
    bias[g] = b_ih[n] + b_hh[n];
  }

  float c[4] = {0.f, 0.f, 0.f, 0.f};
  const int batch0 = m * 16;
  const unsigned short* inpRow = inp + (size_t)(batch0 + col) * SEQ_ * 64 + quad * 8;
  const int myflag = s * 4 + m * 2 + q;
  const int pollflag = (lane >> 1) * 4 + m * 2 + (lane & 1);  // lanes 0..15: (s',q')

  for (int t = 0; t < SEQ_; ++t) {
    f32x4 acc[4];
    #pragma unroll
    for (int g = 0; g < 4; ++g) acc[g] = (f32x4){bias[g], bias[g], bias[g], bias[g]};

    // input projection (independent of h) — issued before the poll
    {
      const s16x8 a0 = *(const s16x8*)(inpRow + (size_t)t * 64);
      const s16x8 a1 = *(const s16x8*)(inpRow + (size_t)t * 64 + 32);
      #pragma unroll
      for (int g = 0; g < 4; ++g)
        acc[g] = __builtin_amdgcn_mfma_f32_16x16x32_bf16(a0, WIf[g][0], acc[g], 0, 0, 0);
      #pragma unroll
      for (int g = 0; g < 4; ++g)
        acc[g] = __builtin_amdgcn_mfma_f32_16x16x32_bf16(a1, WIf[g][1], acc[g], 0, 0, 0);
    }

    if (t > 0) {
      if (lane < 16) {
        const unsigned int* fp = flags + ((size_t)(t - 1) * 32 + pollflag);
        while (__hip_atomic_load(fp, __ATOMIC_RELAXED, __HIP_MEMORY_SCOPE_AGENT)
               != (0x5E000000u | (unsigned)(t - 1))) {}
      }
      __builtin_amdgcn_fence(__ATOMIC_ACQUIRE, "agent");
      const unsigned short* hrow = hs + ((size_t)(t - 1) * 32 + batch0 + col) * 256 + quad * 8;
      s16x8 a[8];
      #pragma unroll
      for (int ks = 0; ks < 8; ++ks) a[ks] = *(const s16x8*)(hrow + ks * 32);
      #pragma unroll
      for (int ks = 0; ks < 8; ++ks)
        #pragma unroll
        for (int g = 0; g < 4; ++g)
          acc[g] = __builtin_amdgcn_mfma_f32_16x16x32_bf16(a[ks], Bf[g][ks], acc[g], 0, 0, 0);
    }

    // lane-local gate nonlinearity + state update (4 batches x 1 dim)
    unsigned short* hp = hs + ((size_t)t * 32 + batch0 + quad * 4) * 256 + (s * 32 + q * 16 + col);
    #pragma unroll
    for (int r = 0; r < 4; ++r) {
      const float gi = acc[0][r], gf = acc[1][r], gg = acc[2][r], go = acc[3][r];
      const float si = 1.f / (1.f + __expf(-gi));
      const float sf = 1.f / (1.f + __expf(-gf));
      const float tg = 2.f / (1.f + __expf(-2.f * gg)) - 1.f;
      const float so = 1.f / (1.f + __expf(-go));
      c[r] = sf * c[r] + si * tg;
      const float tc = 2.f / (1.f + __expf(-2.f * c[r])) - 1.f;
      const unsigned int hv = (unsigned int)f2bf(so * tc);
      unsigned short* p = hp + r * 256;
      asm volatile("global_store_short %0, %1, off sc0 sc1" :: "v"(p), "v"(hv) : "memory");
    }
    asm volatile("s_waitcnt vmcnt(0)" ::: "memory");
    if (lane == 0)
      __hip_atomic_store(flags + ((size_t)t * 32 + myflag), (0x5E000000u | (unsigned)t),
                         __ATOMIC_RELEASE, __HIP_MEMORY_SCOPE_AGENT);
  }
}

// ------------------------------- readout -----------------------------------

// out[b,v,t] = hs[t,b,:] . W_ro[v,:] + b_ro[v]
__global__ __launch_bounds__(256, 1) void k4_outgemm(const unsigned short* __restrict__ hs,
                                                     const float* __restrict__ W_ro,
                                                     const float* __restrict__ b_ro,
                                                     float* __restrict__ out) {
  __shared__ unsigned short WroL[8 * 8 * 64 * 8];   // [slot=nt*8+ks][lane][8], 64KB
  const int tid = threadIdx.x, lane = tid & 63, wave = tid >> 6;
  const int bi = blockIdx.x;
  const int b = bi / 48; const int rem = bi % 48; const int tc = rem >> 1, nh = rem & 1;
  const int col = lane & 15, quad = lane >> 4;

  for (int slot = wave; slot < 64; slot += 4) {
    const int nt = slot >> 3, ks = slot & 7;
    const int v = nh * 128 + nt * 16 + col;
    const int k = ks * 32 + quad * 8;
    const float* src = W_ro + (size_t)v * 256 + k;
    s16x8 pk;
    #pragma unroll
    for (int j = 0; j < 8; ++j) pk[j] = (short)f2bf(src[j]);
    *((s16x8*)WroL + slot * 64 + lane) = pk;
  }
  __syncthreads();

  const int t0 = tc * 128 + wave * 32;
  f32x4 acc[2][8];
  #pragma unroll
  for (int mt = 0; mt < 2; ++mt)
    #pragma unroll
    for (int nt = 0; nt < 8; ++nt) acc[mt][nt] = (f32x4){0.f, 0.f, 0.f, 0.f};

  #pragma unroll
  for (int ks = 0; ks < 8; ++ks) {
    const s16x8 a0 = *(const s16x8*)(hs + ((size_t)(t0 + col) * 32 + b) * 256 + ks * 32 + quad * 8);
    const s16x8 a1 = *(const s16x8*)(hs + ((size_t)(t0 + 16 + col) * 32 + b) * 256 + ks * 32 + quad * 8);
    #pragma unroll
    for (int nt = 0; nt < 8; ++nt) {
      const s16x8 bb = *((const s16x8*)WroL + (nt * 8 + ks) * 64 + lane);
      acc[0][nt] = __builtin_amdgcn_mfma_f32_16x16x32_bf16(a0, bb, acc[0][nt], 0, 0, 0);
      acc[1][nt] = __builtin_amdgcn_mfma_f32_16x16x32_bf16(a1, bb, acc[1][nt], 0, 0, 0);
    }
  }

  #pragma unroll
  for (int nt = 0; nt < 8; ++nt) {
    const int v = nh * 128 + nt * 16 + col;
    const float brv = b_ro[v];
    #pragma unroll
    for (int mt = 0; mt < 2; ++mt) {
      f32x4 o = acc[mt][nt];
      o[0] += brv; o[1] += brv; o[2] += brv; o[3] += brv;
      const int t = t0 + mt * 16 + quad * 4;
      *(f32x4*)(out + ((size_t)b * 256 + v) * SEQ_ + t) = o;
    }
  }
}

// ------------------------------- launcher ----------------------------------

extern "C" void kernel_launch(void* const* d_in, const int* in_sizes, int n_in,
                              void* d_out, int out_size, void* d_ws, size_t ws_size,
                              hipStream_t stream) {
  const float* z       = (const float*)d_in[0];
  const float* theta   = (const float*)d_in[1];
  const float* W_theta = (const float*)d_in[2];
  const float* b_theta = (const float*)d_in[3];
  const float* W_dec   = (const float*)d_in[4];
  const float* b_dec   = (const float*)d_in[5];
  const float* gn_w    = (const float*)d_in[6];
  const float* gn_b    = (const float*)d_in[7];
  const float* emb     = (const float*)d_in[8];
  const float* v_ih    = (const float*)d_in[9];
  const float* g_ih    = (const float*)d_in[10];
  const float* v_hh    = (const float*)d_in[11];
  const float* g_hh    = (const float*)d_in[12];
  const float* b_ih    = (const float*)d_in[13];
  const float* b_hh    = (const float*)d_in[14];
  const float* W_ro    = (const float*)d_in[15];
  const float* b_ro    = (const float*)d_in[16];
  const int*   x_tgt   = (const int*)d_in[17];
  float* out = (float*)d_out;
  char* ws = (char*)d_ws;

  // ws layout (bytes)
  float*          cond  = (float*)(ws + 0);                 //    32768
  float*          x     = (float*)(ws + 32768);             //  8388608
  float*          gnA   = (float*)(ws + 8421376);           //     8192
  float*          gnB   = (float*)(ws + 8429568);           //     8192
  float*          rsih  = (float*)(ws + 8437760);           //     4096
  float*          rshh  = (float*)(ws + 8441856);           //     4096
  unsigned short* WIp   = (unsigned short*)(ws + 8445952);  //   131072
  unsigned short* WBp   = (unsigned short*)(ws + 8577024);  //   524288
  unsigned short* inp   = (unsigned short*)(ws + 9101312);  // 12582912
  unsigned short* hs    = (unsigned short*)(ws + 21684224); // 50331648
  unsigned int*   flags = (unsigned int*)(ws + 72015872);   //   393216
  if (ws_size < 72409088u) return;  // requires ~69.1 MB scratch

  p0_norms  <<<512,  256, 0, stream>>>(v_ih, g_ih, v_hh, g_hh, rsih, rshh);
  p2_packWB <<<1024, 256, 0, stream>>>(v_hh, rshh, WBp);
  p3_packWI <<<256,  256, 0, stream>>>(v_ih, rsih, WIp);
  k1a_cond  <<<32,   256, 0, stream>>>(z, theta, W_theta, b_theta, cond);
  k1b_dec   <<<256,  256, 0, stream>>>(cond, W_dec, b_dec, x);
  k1c_gnstats<<<256, 256, 0, stream>>>(x, gn_w, gn_b, gnA, gnB);
  k1d_inp   <<<256,  256, 0, stream>>>(x, gnA, gnB, emb, x_tgt, inp);
  k3_lstm   <<<8,    256, 0, stream>>>(WBp, WIp, inp, b_ih, b_hh, hs, flags);
  k4_outgemm<<<1536, 256, 0, stream>>>(hs, W_ro, b_ro, out);
}

// Round 3
// 11882.537 us; speedup vs baseline: 1.0627x; 1.0627x over previous
//
#include <hip/hip_runtime.h>
#include <hip/hip_bf16.h>

// ---------------------------------------------------------------------------
// Decoder_20435454395154  — round 3
// LSTM exchange: self-validating tagged ring (no flags, no fences, no asm
// loads, no placement assumptions).
//   * ring[rs][slot16][b32][d16] of 32-bit words: (0x5000|t)<<16 | bf16(h),
//     rs = t & 3. Writer publishes with relaxed SYSTEM-scope u64 atomic
//     stores (cache-bypass bits, NO fence instructions). Fire-and-forget.
//   * Reader re-issues 32 relaxed SYSTEM u64 loads until every dword's high
//     16 bits == 0x5000|(t-1). Every dword carries a tag -> torn/partial
//     arrival and 0xAA poison are detected. One MALL round trip per step.
//   * Batches 0-15 / 16-31 are independent recurrences; within each, wave
//     skew <= 1 step (publish t requires consuming t-1 from all peers), so
//     ring slot reuse (distance 4) can never clobber unread data.
//   * Untagged bf16 hs[t][slot][b][d] written with plain cached stores for
//     the readout GEMM (visible via kernel-boundary flush).
//   * W_hh/W_ih fragments pinned in VGPRs via empty asm (round-1 compiler
//     rematerialized them into the loop: VGPR_Count 120 < 160 resident).
// ---------------------------------------------------------------------------

typedef float  f32x4 __attribute__((ext_vector_type(4)));
typedef short  s16x8 __attribute__((ext_vector_type(8)));

union FragU { unsigned u[4]; s16x8 s; };

__device__ __forceinline__ unsigned short f2bf(float f) {
  union { float f; unsigned u; } v; v.f = f;
  unsigned r = v.u + 0x7FFFu + ((v.u >> 16) & 1u);   // RNE
  return (unsigned short)(r >> 16);
}

#define SEQ_   3072

// ------------------------------- prologue ----------------------------------

__global__ void p0_norms(const float* __restrict__ v_ih, const float* __restrict__ g_ih,
                         const float* __restrict__ v_hh, const float* __restrict__ g_hh,
                         float* __restrict__ rsih, float* __restrict__ rshh) {
  const int w = (blockIdx.x * 256 + threadIdx.x) >> 6;
  const int lane = threadIdx.x & 63;
  if (w < 1024) {
    float v = v_ih[w * 64 + lane];
    float s = v * v;
    #pragma unroll
    for (int o = 32; o > 0; o >>= 1) s += __shfl_xor(s, o);
    if (lane == 0) rsih[w] = g_ih[w] * rsqrtf(s);
  } else {
    const int r = w - 1024;
    f32x4 v = *(const f32x4*)(v_hh + (size_t)r * 256 + lane * 4);
    float s = v[0]*v[0] + v[1]*v[1] + v[2]*v[2] + v[3]*v[3];
    #pragma unroll
    for (int o = 32; o > 0; o >>= 1) s += __shfl_xor(s, o);
    if (lane == 0) rshh[r] = g_hh[r] * rsqrtf(s);
  }
}

// pack W_hh into B-fragment order: [sq(16)][g(4)][ks(8)][lane(64)][8]
__global__ void p2_packWB(const float* __restrict__ v_hh, const float* __restrict__ rshh,
                          unsigned short* __restrict__ WBp) {
  const int o = blockIdx.x * 256 + threadIdx.x;
  const int j = o & 7, l = (o >> 3) & 63, ks = (o >> 9) & 7, g = (o >> 12) & 3, sq = o >> 14;
  const int r = g * 256 + (sq >> 1) * 32 + (sq & 1) * 16 + (l & 15);
  const int k = ks * 32 + (l >> 4) * 8 + j;
  WBp[o] = f2bf(v_hh[(size_t)r * 256 + k] * rshh[r]);
}

// pack W_ih: [sq(16)][g(4)][ks(2)][lane(64)][8]
__global__ void p3_packWI(const float* __restrict__ v_ih, const float* __restrict__ rsih,
                          unsigned short* __restrict__ WIp) {
  const int o = blockIdx.x * 256 + threadIdx.x;
  const int j = o & 7, l = (o >> 3) & 63, ks = (o >> 9) & 1, g = (o >> 10) & 3, sq = o >> 12;
  const int r = g * 256 + (sq >> 1) * 32 + (sq & 1) * 16 + (l & 15);
  const int k = ks * 32 + (l >> 4) * 8 + j;
  WIp[o] = f2bf(v_ih[(size_t)r * 64 + k] * rsih[r]);
}

__global__ void k1a_cond(const float* __restrict__ z, const float* __restrict__ theta,
                         const float* __restrict__ W_theta, const float* __restrict__ b_theta,
                         float* __restrict__ cond) {
  const int i = blockIdx.x * 256 + threadIdx.x;
  const int b = i >> 8, n = i & 255;
  cond[i] = z[i] + theta[b*2+0] * W_theta[n*2+0] + theta[b*2+1] * W_theta[n*2+1] + b_theta[n];
}

__global__ __launch_bounds__(256) void k1b_dec(const float* __restrict__ cond,
                                               const float* __restrict__ W_dec,
                                               const float* __restrict__ b_dec,
                                               float* __restrict__ x) {
  const int r = blockIdx.x * 256 + threadIdx.x;
  float acc[32];
  const float bd = b_dec[r];
  #pragma unroll
  for (int b = 0; b < 32; ++b) acc[b] = bd;
  const f32x4* wp = (const f32x4*)(W_dec + (size_t)r * 256);
  for (int k4 = 0; k4 < 64; ++k4) {
    const f32x4 w = wp[k4];
    #pragma unroll
    for (int b = 0; b < 32; ++b) {
      const float* cp = cond + b * 256 + k4 * 4;
      acc[b] += w[0]*cp[0] + w[1]*cp[1] + w[2]*cp[2] + w[3]*cp[3];
    }
  }
  #pragma unroll
  for (int b = 0; b < 32; ++b) x[(size_t)b * 65536 + r] = acc[b];
}

__global__ void k1c_gnstats(const float* __restrict__ x, const float* __restrict__ gn_w,
                            const float* __restrict__ gn_b,
                            float* __restrict__ gnA, float* __restrict__ gnB) {
  __shared__ float sS[256], sQ[256];
  const int b = blockIdx.x >> 3, g = blockIdx.x & 7;
  const float* xp = x + (size_t)b * 65536 + g * 8192;
  float s = 0.f, qq = 0.f;
  for (int i = threadIdx.x; i < 8192; i += 256) { float v = xp[i]; s += v; qq += v * v; }
  sS[threadIdx.x] = s; sQ[threadIdx.x] = qq; __syncthreads();
  for (int o = 128; o > 0; o >>= 1) {
    if (threadIdx.x < o) { sS[threadIdx.x] += sS[threadIdx.x+o]; sQ[threadIdx.x] += sQ[threadIdx.x+o]; }
    __syncthreads();
  }
  if (threadIdx.x < 8) {
    const float mu  = sS[0] * (1.f / 8192.f);
    const float var = sQ[0] * (1.f / 8192.f) - mu * mu;
    const float rstd = rsqrtf(var + 1e-5f);
    const int c = g * 8 + threadIdx.x;
    const float a = gn_w[c] * rstd;
    gnA[b*64+c] = a; gnB[b*64+c] = gn_b[c] - mu * a;
  }
}

__global__ void k1d_inp(const float* __restrict__ x, const float* __restrict__ gnA,
                        const float* __restrict__ gnB, const float* __restrict__ emb,
                        const int* __restrict__ xt, unsigned short* __restrict__ inp) {
  __shared__ float xT[128 * 65];
  const int b = blockIdx.x >> 3, pt = blockIdx.x & 7, p0 = pt * 128;
  const int tid = threadIdx.x;
  for (int i = tid; i < 8192; i += 256) {
    const int p = i & 127, ch = i >> 7;
    float v = x[(size_t)b * 65536 + ch * 1024 + p0 + p];
    xT[p * 65 + ch] = v * gnA[b*64+ch] + gnB[b*64+ch];
  }
  __syncthreads();
  const int wave = tid >> 6, lane = tid & 63;
  for (int row = wave; row < 384; row += 4) {
    const int c3 = row / 128, p = row % 128;
    const int t = c3 * 1024 + p0 + p;
    float v = xT[p * 65 + lane];
    if (t > 0) {
      const int tok = xt[b * SEQ_ + t - 1];
      v += emb[tok * 64 + lane];
    }
    inp[((size_t)b * SEQ_ + t) * 64 + lane] = f2bf(v);
  }
}

// ------------------------------- recurrence --------------------------------

__global__ __launch_bounds__(256, 1) void k3_lstm(
    const unsigned short* __restrict__ WBp, const unsigned short* __restrict__ WIp,
    const unsigned short* __restrict__ inp, const float* __restrict__ b_ih,
    const float* __restrict__ b_hh, unsigned short* __restrict__ hs,
    unsigned long long* __restrict__ ring64) {
  const int s = blockIdx.x;                   // 0..7  h-dim slice
  const int tid = threadIdx.x;
  const int wave = tid >> 6, lane = tid & 63;
  const int m = wave >> 1, q = wave & 1;      // batch half, dim sub-slice
  const int col = lane & 15, quad = lane >> 4;
  const int sq = s * 2 + q;
  const int batch0 = m * 16;

  __shared__ unsigned xch32[4][16][16];       // [wave][row(batch%16)][dim] tagged

  // ---- resident weight fragments (pinned) ----
  s16x8 Bf[4][8];
  #pragma unroll
  for (int g = 0; g < 4; ++g)
    #pragma unroll
    for (int ks = 0; ks < 8; ++ks) {
      Bf[g][ks] = ((const s16x8*)WBp)[((sq * 4 + g) * 8 + ks) * 64 + lane];
      asm volatile("" : "+v"(Bf[g][ks]));
    }
  s16x8 WIf[4][2];
  #pragma unroll
  for (int g = 0; g < 4; ++g)
    #pragma unroll
    for (int ks = 0; ks < 2; ++ks) {
      WIf[g][ks] = ((const s16x8*)WIp)[((sq * 4 + g) * 2 + ks) * 64 + lane];
      asm volatile("" : "+v"(WIf[g][ks]));
    }
  float bias[4];
  #pragma unroll
  for (int g = 0; g < 4; ++g) {
    const int n = g * 256 + s * 32 + q * 16 + col;
    bias[g] = b_ih[n] + b_hh[n];
  }

  float c[4] = {0.f, 0.f, 0.f, 0.f};
  const unsigned short* inpRow = inp + (size_t)(batch0 + col) * SEQ_ * 64 + quad * 8;

  // reader: u64 index bases per ks (within one ring slice), rs adds 4096
  int rdBase[8];
  #pragma unroll
  for (int ks = 0; ks < 8; ++ks) {
    const int slot = 2 * ks + (quad >> 1);
    rdBase[ks] = ((slot * 32 + batch0 + col) * 16 + (quad & 1) * 8) >> 1;
  }
  // writer: u64 index base (within one ring slice)
  const int wrow = lane >> 2, wd0 = (lane & 3) * 4;
  const int wrBase = ((sq * 32 + batch0 + wrow) * 16 + wd0) >> 1;
  unsigned short* hsBase = hs + ((size_t)sq * 32 + batch0 + wrow) * 16 + wd0;

  for (int t = 0; t < SEQ_; ++t) {
    f32x4 acc[4];
    #pragma unroll
    for (int g = 0; g < 4; ++g) acc[g] = (f32x4){bias[g], bias[g], bias[g], bias[g]};

    // input projection (independent of h) — before the poll
    {
      const s16x8 a0 = *(const s16x8*)(inpRow + (size_t)t * 64);
      const s16x8 a1 = *(const s16x8*)(inpRow + (size_t)t * 64 + 32);
      #pragma unroll
      for (int g = 0; g < 4; ++g)
        acc[g] = __builtin_amdgcn_mfma_f32_16x16x32_bf16(a0, WIf[g][0], acc[g], 0, 0, 0);
      #pragma unroll
      for (int g = 0; g < 4; ++g)
        acc[g] = __builtin_amdgcn_mfma_f32_16x16x32_bf16(a1, WIf[g][1], acc[g], 0, 0, 0);
    }

    if (t > 0) {
      const int rs = (t - 1) & 3;
      const unsigned tagHi = (0x5000u | (unsigned)(t - 1)) << 16;
      unsigned long long v[32];
      bool ok = false;
      do {
        #pragma unroll
        for (int ks = 0; ks < 8; ++ks)
          #pragma unroll
          for (int j = 0; j < 4; ++j)
            v[ks * 4 + j] = __hip_atomic_load(ring64 + rs * 4096 + rdBase[ks] + j,
                                              __ATOMIC_RELAXED, __HIP_MEMORY_SCOPE_SYSTEM);
        unsigned r = 0;
        #pragma unroll
        for (int i = 0; i < 32; ++i) {
          r |= ((unsigned)v[i] ^ tagHi);
          r |= ((unsigned)(v[i] >> 32) ^ tagHi);
        }
        ok = ((r >> 16) == 0);
      } while (!ok);

      #pragma unroll
      for (int ks = 0; ks < 8; ++ks) {
        FragU f;
        #pragma unroll
        for (int j = 0; j < 4; ++j) {
          const unsigned lo = (unsigned)v[ks * 4 + j];
          const unsigned hi = (unsigned)(v[ks * 4 + j] >> 32);
          f.u[j] = (lo & 0xFFFFu) | (hi << 16);
        }
        #pragma unroll
        for (int g = 0; g < 4; ++g)
          acc[g] = __builtin_amdgcn_mfma_f32_16x16x32_bf16(f.s, Bf[g][ks], acc[g], 0, 0, 0);
      }
    }

    // gate nonlinearity + state update (4 batches x 1 dim per lane)
    const unsigned tagOut = (0x5000u | (unsigned)t) << 16;
    #pragma unroll
    for (int r = 0; r < 4; ++r) {
      const float gi = acc[0][r], gf = acc[1][r], gg = acc[2][r], go = acc[3][r];
      const float si = 1.f / (1.f + __expf(-gi));
      const float sf = 1.f / (1.f + __expf(-gf));
      const float tg = 2.f / (1.f + __expf(-2.f * gg)) - 1.f;
      const float so = 1.f / (1.f + __expf(-go));
      c[r] = sf * c[r] + si * tg;
      const float tc = 2.f / (1.f + __expf(-2.f * c[r])) - 1.f;
      xch32[wave][quad * 4 + r][col] = tagOut | (unsigned)f2bf(so * tc);
    }
    asm volatile("s_waitcnt lgkmcnt(0)" ::: "memory");   // intra-wave repack visible
    const unsigned t0 = xch32[wave][wrow][wd0 + 0];
    const unsigned t1 = xch32[wave][wrow][wd0 + 1];
    const unsigned t2 = xch32[wave][wrow][wd0 + 2];
    const unsigned t3 = xch32[wave][wrow][wd0 + 3];
    const int rsOut = t & 3;
    __hip_atomic_store(ring64 + rsOut * 4096 + wrBase + 0,
                       (unsigned long long)t0 | ((unsigned long long)t1 << 32),
                       __ATOMIC_RELAXED, __HIP_MEMORY_SCOPE_SYSTEM);
    __hip_atomic_store(ring64 + rsOut * 4096 + wrBase + 1,
                       (unsigned long long)t2 | ((unsigned long long)t3 << 32),
                       __ATOMIC_RELAXED, __HIP_MEMORY_SCOPE_SYSTEM);
    // untagged bf16 for the readout GEMM (plain cached store)
    uint2 hv;
    hv.x = (t0 & 0xFFFFu) | (t1 << 16);
    hv.y = (t2 & 0xFFFFu) | (t3 << 16);
    *(uint2*)(hsBase + (size_t)t * 8192) = hv;
  }
}

// ------------------------------- readout -----------------------------------

// out[b,v,t] = hs[t,b,:] . W_ro[v,:] + b_ro[v]; hs in [t][slot][b][d] layout
__global__ __launch_bounds__(256, 1) void k4_outgemm(const unsigned short* __restrict__ ex,
                                                     const float* __restrict__ W_ro,
                                                     const float* __restrict__ b_ro,
                                                     float* __restrict__ out) {
  __shared__ unsigned short WroL[8 * 8 * 64 * 8];   // [slot=nt*8+ks][lane][8], 64KB
  const int tid = threadIdx.x, lane = tid & 63, wave = tid >> 6;
  const int bi = blockIdx.x;
  const int b = bi / 48; const int rem = bi % 48; const int tc = rem >> 1, nh = rem & 1;
  const int col = lane & 15, quad = lane >> 4;

  for (int slot = wave; slot < 64; slot += 4) {
    const int nt = slot >> 3, ks = slot & 7;
    const int v = nh * 128 + nt * 16 + col;
    const int k = ks * 32 + quad * 8;
    const float* src = W_ro + (size_t)v * 256 + k;
    s16x8 pk;
    #pragma unroll
    for (int j = 0; j < 8; ++j) pk[j] = (short)f2bf(src[j]);
    *((s16x8*)WroL + slot * 64 + lane) = pk;
  }
  __syncthreads();

  const int t0 = tc * 128 + wave * 32;
  f32x4 acc[2][8];
  #pragma unroll
  for (int mt = 0; mt < 2; ++mt)
    #pragma unroll
    for (int nt = 0; nt < 8; ++nt) acc[mt][nt] = (f32x4){0.f, 0.f, 0.f, 0.f};

  #pragma unroll
  for (int ks = 0; ks < 8; ++ks) {
    const int slot = 2 * ks + (quad >> 1), off = (quad & 1) * 8;
    const s16x8 a0 = *(const s16x8*)(ex + (((size_t)(t0 + col) * 16 + slot) * 32 + b) * 16 + off);
    const s16x8 a1 = *(const s16x8*)(ex + (((size_t)(t0 + 16 + col) * 16 + slot) * 32 + b) * 16 + off);
    #pragma unroll
    for (int nt = 0; nt < 8; ++nt) {
      const s16x8 bb = *((const s16x8*)WroL + (nt * 8 + ks) * 64 + lane);
      acc[0][nt] = __builtin_amdgcn_mfma_f32_16x16x32_bf16(a0, bb, acc[0][nt], 0, 0, 0);
      acc[1][nt] = __builtin_amdgcn_mfma_f32_16x16x32_bf16(a1, bb, acc[1][nt], 0, 0, 0);
    }
  }

  #pragma unroll
  for (int nt = 0; nt < 8; ++nt) {
    const int v = nh * 128 + nt * 16 + col;
    const float brv = b_ro[v];
    #pragma unroll
    for (int mt = 0; mt < 2; ++mt) {
      f32x4 o = acc[mt][nt];
      o[0] += brv; o[1] += brv; o[2] += brv; o[3] += brv;
      const int t = t0 + mt * 16 + quad * 4;
      *(f32x4*)(out + ((size_t)b * 256 + v) * SEQ_ + t) = o;
    }
  }
}

// ------------------------------- launcher ----------------------------------

extern "C" void kernel_launch(void* const* d_in, const int* in_sizes, int n_in,
                              void* d_out, int out_size, void* d_ws, size_t ws_size,
                              hipStream_t stream) {
  const float* z       = (const float*)d_in[0];
  const float* theta   = (const float*)d_in[1];
  const float* W_theta = (const float*)d_in[2];
  const float* b_theta = (const float*)d_in[3];
  const float* W_dec   = (const float*)d_in[4];
  const float* b_dec   = (const float*)d_in[5];
  const float* gn_w    = (const float*)d_in[6];
  const float* gn_b    = (const float*)d_in[7];
  const float* emb     = (const float*)d_in[8];
  const float* v_ih    = (const float*)d_in[9];
  const float* g_ih    = (const float*)d_in[10];
  const float* v_hh    = (const float*)d_in[11];
  const float* g_hh    = (const float*)d_in[12];
  const float* b_ih    = (const float*)d_in[13];
  const float* b_hh    = (const float*)d_in[14];
  const float* W_ro    = (const float*)d_in[15];
  const float* b_ro    = (const float*)d_in[16];
  const int*   x_tgt   = (const int*)d_in[17];
  float* out = (float*)d_out;
  char* ws = (char*)d_ws;

  // ws layout (bytes) — same footprint as round 1 (proven to fit)
  float*              cond  = (float*)(ws + 0);                 //    32768
  float*              x     = (float*)(ws + 32768);             //  8388608
  float*              gnA   = (float*)(ws + 8421376);           //     8192
  float*              gnB   = (float*)(ws + 8429568);           //     8192
  float*              rsih  = (float*)(ws + 8437760);           //     4096
  float*              rshh  = (float*)(ws + 8441856);           //     4096
  unsigned short*     WIp   = (unsigned short*)(ws + 8445952);  //   131072
  unsigned short*     WBp   = (unsigned short*)(ws + 8577024);  //   524288
  unsigned short*     inp   = (unsigned short*)(ws + 9101312);  // 12582912
  unsigned short*     hs    = (unsigned short*)(ws + 21684224); // 50331648  [t][slot16][b32][16]
  unsigned long long* ring64= (unsigned long long*)(ws + 72015872); // 131072 (4-deep tagged ring)
  if (ws_size < 72409088u) return;

  p0_norms  <<<512,  256, 0, stream>>>(v_ih, g_ih, v_hh, g_hh, rsih, rshh);
  p2_packWB <<<1024, 256, 0, stream>>>(v_hh, rshh, WBp);
  p3_packWI <<<256,  256, 0, stream>>>(v_ih, rsih, WIp);
  k1a_cond  <<<32,   256, 0, stream>>>(z, theta, W_theta, b_theta, cond);
  k1b_dec   <<<256,  256, 0, stream>>>(cond, W_dec, b_dec, x);
  k1c_gnstats<<<256, 256, 0, stream>>>(x, gn_w, gn_b, gnA, gnB);
  k1d_inp   <<<256,  256, 0, stream>>>(x, gnA, gnB, emb, x_tgt, inp);
  k3_lstm   <<<8,    256, 0, stream>>>(WBp, WIp, inp, b_ih, b_hh, hs, ring64);
  k4_outgemm<<<1536, 256, 0, stream>>>(hs, W_ro, b_ro, out);
}